// Round 12
// baseline (513.535 us; speedup 1.0000x reference)
//
#include <hip/hip_runtime.h>
#include <hip/hip_bf16.h>
#include <stdint.h>

#define SEQLEN 512
#define NBATCH 64
#define KDIM   512
#define HDIM   1024
#define MTOT   (SEQLEN * NBATCH)   // 32768
#define NTOT   (3 * HDIM)          // 3072
#define STRIDE (NBATCH * HDIM)     // 65536

typedef __attribute__((ext_vector_type(4))) float f32x4;
typedef _Float16 f16x8 __attribute__((ext_vector_type(8)));

// ---------- merged conversion: x and U -> (hi, lo) fp16 planes -----------
// 3-pass MFMA (AhBh+AhBl+AlBh) ~= fp32 GEMM (r5: 2-pass fails at 0.51).
#define XTHREADS (MTOT * KDIM / 8)   // 2,097,152
#define UTHREADS (NTOT * KDIM / 8)   //   196,608
__global__ __launch_bounds__(256) void cvt_all(const float* __restrict__ x,
                                               const float* __restrict__ Uc,
                                               const float* __restrict__ Ua,
                                               const float* __restrict__ Uh,
                                               _Float16* __restrict__ xh,
                                               _Float16* __restrict__ xl,
                                               _Float16* __restrict__ uh,
                                               _Float16* __restrict__ ul) {
    int i = blockIdx.x * 256 + threadIdx.x;
    const float* src;
    _Float16 *dh, *dl;
    size_t off;
    if (i < XTHREADS) {
        src = x + (size_t)i * 8;
        off = (size_t)i * 8;
        dh = xh; dl = xl;
    } else {
        int u = i - XTHREADS;
        int n = u >> 6;
        int kb = (u & 63) * 8;
        src = ((n < HDIM) ? (Uc + (size_t)n * KDIM)
             : (n < 2 * HDIM) ? (Ua + (size_t)(n - HDIM) * KDIM)
             : (Uh + (size_t)(n - 2 * HDIM) * KDIM)) + kb;
        off = (size_t)n * KDIM + kb;
        dh = uh; dl = ul;
    }
    const float4* s = (const float4*)src;
    float4 a = s[0], b = s[1];
    float v[8] = {a.x, a.y, a.z, a.w, b.x, b.y, b.z, b.w};
    f16x8 hi, lo;
#pragma unroll
    for (int j = 0; j < 8; ++j) {
        _Float16 h = (_Float16)v[j];
        hi[j] = h;
        lo[j] = (_Float16)(v[j] - (float)h);
    }
    *(f16x8*)(dh + off) = hi;
    *(f16x8*)(dl + off) = lo;
}

// --------- GEMM: proj[M][3072] = (Xh+Xl)·(Uh+Ul)^T, 3-pass split ---------
// Round-12: consumer-free read-ahead. Per tile kt the body contains
//   {ds_reads of tile kt+1 (consumed NEXT body), stage(kt+2), MFMA(kt)}
// so no ds_read has an lgkm consumer in its own inter-barrier region ->
// LDS pipe (  ~1536 cyc) overlaps MFMA issue window (~1862 cyc) structurally.
// Triple buffer (48 KB x 3): write target (kt+2)%3 disjoint from both read
// buffers. Boundary: vmcnt(0) drains the single 6-load stage batch issued a
// full body (~1900 cyc) earlier -> ~free; one raw s_barrier per tile.
// 16x16x32 MFMA only (32x32 abandoned: r8/r11 conflict mechanism unresolved).
#define BM 256
#define BN 128
#define BK 32
#define NT_N (NTOT / BN)            // 24
#define GRID ((MTOT / BM) * NT_N)   // 3072
#define KT_N (KDIM / BK)            // 16
// halfword offsets within one 48 KB buffer
#define OFF_AH 0
#define OFF_AL 8192
#define OFF_BH 16384
#define OFF_BL 20480
#define BUF_HW 24576

__device__ __forceinline__ void gload16(const _Float16* g, _Float16* l) {
    __builtin_amdgcn_global_load_lds((const __attribute__((address_space(1))) void*)g,
                                     (__attribute__((address_space(3))) void*)l,
                                     16, 0, 0);
}

__device__ __forceinline__ f32x4 mfma16(f16x8 a, f16x8 b, f32x4 c) {
    return __builtin_amdgcn_mfma_f32_16x16x32_f16(a, b, c, 0, 0, 0);
}

__global__ __launch_bounds__(512, 2) void gemm_f16x2(const _Float16* __restrict__ Ah,
                                                     const _Float16* __restrict__ Al,
                                                     const _Float16* __restrict__ Bh,
                                                     const _Float16* __restrict__ Bl,
                                                     float* __restrict__ pc,
                                                     float* __restrict__ pa,
                                                     float* __restrict__ ph) {
    __shared__ _Float16 lds[3][BUF_HW];   // 147456 B -> 1 block/CU

    int bid  = blockIdx.x;          // default order, A-panel-major
    int bm   = bid / NT_N;
    int bn   = bid % NT_N;
    int tid  = threadIdx.x;
    int lane = tid & 63;
    int wave = tid >> 6;
    int wr   = wave >> 1;           // 0..3 (M quarter, 64 rows)
    int wc   = wave & 1;            // 0..1 (N half, 64 cols)

    // staging (T2 source-side chunk permute; measured conflict-free r3-r7)
    size_t row_off = (size_t)(tid >> 2) * KDIM
                   + (size_t)(((tid & 3) ^ ((tid >> 3) & 3)) * 8);
    const _Float16* gAh = Ah + (size_t)bm * BM * KDIM + row_off;
    const _Float16* gAl = Al + (size_t)bm * BM * KDIM + row_off;
    const _Float16* gBh = Bh + (size_t)bn * BN * KDIM + row_off;
    const _Float16* gBl = Bl + (size_t)bn * BN * KDIM + row_off;
    const size_t P128 = (size_t)128 * KDIM;   // +128 rows in global
    int t8 = tid * 8;

// 6 loads/tile: A planes 2 each (256 rows), B planes 1 each (128 rows)
#define STAGE(buf, kt) do { int _g = (kt) * BK;                                \
    gload16(gAh + _g,        &lds[buf][OFF_AH + t8]);                          \
    gload16(gAh + P128 + _g, &lds[buf][OFF_AH + 4096 + t8]);                   \
    gload16(gAl + _g,        &lds[buf][OFF_AL + t8]);                          \
    gload16(gAl + P128 + _g, &lds[buf][OFF_AL + 4096 + t8]);                   \
    gload16(gBh + _g,        &lds[buf][OFF_BH + t8]);                          \
    gload16(gBl + _g,        &lds[buf][OFF_BL + t8]); } while (0)

    f32x4 acc[4][4];
#pragma unroll
    for (int i = 0; i < 4; ++i)
#pragma unroll
        for (int j = 0; j < 4; ++j)
            acc[i][j] = (f32x4){0.f, 0.f, 0.f, 0.f};

    int ro = lane & 15;
    int ko = ((lane >> 4) ^ ((lane >> 1) & 3)) * 8;   // read-side swizzle

    // two named fragment sets (rule #20: no runtime indexing)
    f16x8 aX[4][2], bX[4][2], aY[4][2], bY[4][2];

#define READF(aS, bS, cb) do { _Pragma("unroll")                               \
    for (int i = 0; i < 4; ++i) {                                              \
        int row = wr * 64 + i * 16 + ro;                                       \
        aS[i][0] = *(const f16x8*)(&lds[cb][OFF_AH + row * BK + ko]);          \
        aS[i][1] = *(const f16x8*)(&lds[cb][OFF_AL + row * BK + ko]);          \
    }                                                                          \
    _Pragma("unroll")                                                          \
    for (int j = 0; j < 4; ++j) {                                              \
        int row = wc * 64 + j * 16 + ro;                                       \
        bS[j][0] = *(const f16x8*)(&lds[cb][OFF_BH + row * BK + ko]);          \
        bS[j][1] = *(const f16x8*)(&lds[cb][OFF_BL + row * BK + ko]);          \
    } } while (0)

#define MFMAS(aS, bS) _Pragma("unroll")                                        \
    for (int i = 0; i < 4; ++i) _Pragma("unroll")                              \
        for (int j = 0; j < 4; ++j) {                                          \
            f32x4 c = acc[i][j];                                               \
            c = mfma16(aS[i][0], bS[j][1], c);   /* Ah·Bl */                   \
            c = mfma16(aS[i][1], bS[j][0], c);   /* Al·Bh */                   \
            c = mfma16(aS[i][0], bS[j][0], c);   /* Ah·Bh */                   \
            acc[i][j] = c;                                                     \
        }

// body kt: boundary (vmcnt0 drains stage(kt+1), barrier), read tile kt+1
// frags (no consumer here), stage tile kt+2, MFMA tile kt (operands from
// previous body's reads).
#define BODY(kt, ACUR, BCUR, ANXT, BNXT, cbn, cbt) do {                        \
    __builtin_amdgcn_sched_barrier(0);                                         \
    asm volatile("s_waitcnt vmcnt(0)" ::: "memory");                           \
    __builtin_amdgcn_s_barrier();                                              \
    __builtin_amdgcn_sched_barrier(0);                                         \
    if ((kt) + 1 < KT_N) READF(ANXT, BNXT, cbn);                               \
    if ((kt) + 2 < KT_N) STAGE(cbt, (kt) + 2);                                 \
    __builtin_amdgcn_s_setprio(1);                                             \
    MFMAS(ACUR, BCUR);                                                         \
    __builtin_amdgcn_s_setprio(0);                                             \
} while (0)

    // prologue: stage tiles 0,1 -> bufs 0,1; counted drain of stage(0);
    // barrier publishes; read tile-0 frags into set X.
    STAGE(0, 0);
    STAGE(1, 1);
    __builtin_amdgcn_sched_barrier(0);
    asm volatile("s_waitcnt vmcnt(6)" ::: "memory");   // stage(0) done, (1) flying
    __builtin_amdgcn_s_barrier();
    __builtin_amdgcn_sched_barrier(0);
    READF(aX, bX, 0);

    int c0 = 0, c1 = 1, c2 = 2;     // cur, next, stage-target buffers
    for (int kt = 0; kt < KT_N; kt += 2) {
        BODY(kt,     aX, bX, aY, bY, c1, c2);
        BODY(kt + 1, aY, bY, aX, bX, c2, c0);
        int t = c0; c0 = c2; c2 = c1; c1 = t;   // advance by 2 tiles
    }

    // epilogue: D col=lane&15 (N), row=(lane>>4)*4+r (M)  [m89-verified]
    // BN=128 divides HDIM -> whole block routes to one output buffer.
    // ai-outer / j-inner (r9 lesson: j-outer caused 3.7x write amplification)
    int n0 = bn * BN;
    float* outp = (n0 < HDIM) ? pc : (n0 < 2 * HDIM) ? pa : ph;
    int nb = n0 & (HDIM - 1);
#pragma unroll
    for (int i = 0; i < 4; ++i)
#pragma unroll
        for (int r = 0; r < 4; ++r) {
            int m = bm * BM + wr * 64 + i * 16 + (lane >> 4) * 4 + r;
#pragma unroll
            for (int j = 0; j < 4; ++j) {
                int n = nb + wc * 64 + j * 16 + (lane & 15);
                outp[(size_t)m * HDIM + n] = acc[i][j][r];
            }
        }
#undef STAGE
#undef READF
#undef MFMAS
#undef BODY
}

// ------------------------- recurrence ------------------------------------
// one thread per (b,j); 65536 threads; depth-16 register prefetch pipeline
// (PF=16: 48 outstanding loads <= 63 vmcnt capacity; PF=32 exceeded it).
// libm transcendentals (r8 measured: fast variants null — BW/latency-bound).
__global__ __launch_bounds__(256) void recur(const float* __restrict__ pc_a,
                                             const float* __restrict__ pa_a,
                                             float* out,
                                             const float* __restrict__ h0,
                                             const float* __restrict__ wc_,
                                             const float* __restrict__ bc_,
                                             const float* __restrict__ wa_,
                                             const float* __restrict__ ba_,
                                             const float* __restrict__ bh_) {
    int idx = blockIdx.x * 256 + threadIdx.x;
    int j = idx & (HDIM - 1);
    float h  = h0[idx];
    float wc = wc_[j], bc = bc_[j];
    float wa = wa_[j], ba = ba_[j];
    float bh = bh_[j];

#define PF 16
    float pc[PF], pa[PF], ph[PF];
#pragma unroll
    for (int u = 0; u < PF; ++u) {
        pc[u] = pc_a[(size_t)u * STRIDE + idx];
        pa[u] = pa_a[(size_t)u * STRIDE + idx];
        ph[u] = out [(size_t)u * STRIDE + idx];
    }

    for (int sb = 0; sb < SEQLEN; sb += PF) {
#pragma unroll
        for (int u = 0; u < PF; ++u) {
            int s = sb + u;
            float vc = pc[u], va = pa[u], vh = ph[u];
            int sp = s + PF; sp = (sp < SEQLEN) ? sp : (SEQLEN - 1);
            pc[u] = pc_a[(size_t)sp * STRIDE + idx];
            pa[u] = pa_a[(size_t)sp * STRIDE + idx];
            ph[u] = out [(size_t)sp * STRIDE + idx];

            float zc = (vc + bc) + wc * h;
            float za = (va + ba) + wa * h;
            float c  = 1.0f / (1.0f + expf(-zc));
            float a  = 1.0f + tanhf(za);
            float ht = tanhf((vh + bh) + a * h);
            h = c * h + (1.0f - c) * ht;
            out[(size_t)s * STRIDE + idx] = h;
        }
    }
    out[(size_t)SEQLEN * STRIDE + idx] = h;   // hn
}

// --------------------------- launch --------------------------------------
extern "C" void kernel_launch(void* const* d_in, const int* in_sizes, int n_in,
                              void* d_out, int out_size, void* d_ws, size_t ws_size,
                              hipStream_t stream) {
    const float* x_seq = (const float*)d_in[0];
    const float* h0    = (const float*)d_in[1];
    const float* U_c   = (const float*)d_in[2];
    const float* w_c   = (const float*)d_in[3];
    const float* b_c   = (const float*)d_in[4];
    const float* U_a   = (const float*)d_in[5];
    const float* w_a   = (const float*)d_in[6];
    const float* b_a   = (const float*)d_in[7];
    const float* U_h   = (const float*)d_in[8];
    const float* b_h   = (const float*)d_in[9];
    float* out = (float*)d_out;

    char* ws = (char*)d_ws;
    const size_t MB = 1024 * 1024;
    float*    ws_pc = (float*)ws;                        // 128 MB
    float*    ws_pa = (float*)(ws + 128 * MB);           // 128 MB
    _Float16* x_hi  = (_Float16*)(ws + 256 * MB);        // 32 MB
    _Float16* x_lo  = (_Float16*)(ws + 288 * MB);        // 32 MB
    _Float16* u_hi  = (_Float16*)(ws + 320 * MB);        // 3 MB
    _Float16* u_lo  = (_Float16*)(ws + 323 * MB);        // 3 MB

    cvt_all<<<dim3((XTHREADS + UTHREADS) / 256), dim3(256), 0, stream>>>(
        x_seq, U_c, U_a, U_h, x_hi, x_lo, u_hi, u_lo);
    gemm_f16x2<<<dim3(GRID), dim3(512), 0, stream>>>(
        x_hi, x_lo, u_hi, u_lo, ws_pc, ws_pa, out);
    recur<<<dim3(STRIDE / 256), dim3(256), 0, stream>>>(ws_pc, ws_pa, out, h0,
                                                        w_c, b_c, w_a, b_a, b_h);
}